// Round 2
// baseline (2008.305 us; speedup 1.0000x reference)
//
#include <hip/hip_runtime.h>
#include <hip/hip_bf16.h>
#include <stdint.h>
#include <stdio.h>

// Problem sizes (fixed by setup_inputs)
#define B_ 4
#define S_ 2048
#define D_ 2048
#define P_ 2729
#define NP 2816            // P padded to multiple of 256
#define M_ (B_ * S_)       // 8192

#define SCHUNK 128
#define NCHUNK (S_ / SCHUNK)   // 16

typedef __attribute__((ext_vector_type(8))) short bh8;   // 8 x bf16 (4 VGPRs)
typedef __attribute__((ext_vector_type(4))) float fx4;   // MFMA accumulator

static __device__ __forceinline__ float bf2f(unsigned short u) {
  union { unsigned int i; float f; } c;
  c.i = ((unsigned int)u) << 16;
  return c.f;
}
static __device__ __forceinline__ unsigned short f2bf(float f) {
  union { __hip_bfloat16 h; unsigned short u; } c;
  c.h = __float2bfloat16(f);
  return c.u;
}
static __device__ __forceinline__ float fast_tanh(float x) {
  return 1.0f - 2.0f / (__expf(2.0f * x) + 1.0f);
}
static __device__ __forceinline__ float gate_act(float z) {
  float sc = 15.0f * fast_tanh(z * (1.0f / 15.0f));
  return 1.0f / (1.0f + __expf(-sc));
}

static __device__ __forceinline__ void gload_lds16(const ushort* g, ushort* l) {
  __builtin_amdgcn_global_load_lds(
      (const __attribute__((address_space(1))) unsigned int*)g,
      (__attribute__((address_space(3))) unsigned int*)l, 16, 0, 0);
}

// ---------------- RMSNorm + bf16 cast ----------------
__global__ __launch_bounds__(256) void rmsnorm_kernel(const float* __restrict__ x,
                                                      const float* __restrict__ w,
                                                      __hip_bfloat16* __restrict__ xn) {
  int row = blockIdx.x;
  const float4* xr = (const float4*)(x + (size_t)row * D_);
  int t = threadIdx.x;
  float4 v0 = xr[t];
  float4 v1 = xr[t + 256];
  float ss = v0.x * v0.x + v0.y * v0.y + v0.z * v0.z + v0.w * v0.w +
             v1.x * v1.x + v1.y * v1.y + v1.z * v1.z + v1.w * v1.w;
#pragma unroll
  for (int off = 32; off > 0; off >>= 1) ss += __shfl_down(ss, off);
  __shared__ float red[4];
  if ((t & 63) == 0) red[t >> 6] = ss;
  __syncthreads();
  float scale = rsqrtf((red[0] + red[1] + red[2] + red[3]) * (1.0f / (float)D_) + 1e-6f);
  const float4* wp = (const float4*)w;
  float4 w0 = wp[t], w1 = wp[t + 256];
  ushort4 o0, o1;
  o0.x = f2bf(v0.x * scale * w0.x);
  o0.y = f2bf(v0.y * scale * w0.y);
  o0.z = f2bf(v0.z * scale * w0.z);
  o0.w = f2bf(v0.w * scale * w0.w);
  o1.x = f2bf(v1.x * scale * w1.x);
  o1.y = f2bf(v1.y * scale * w1.y);
  o1.z = f2bf(v1.z * scale * w1.z);
  o1.w = f2bf(v1.w * scale * w1.w);
  ushort4* xo = (ushort4*)(xn + (size_t)row * D_);
  xo[t] = o0;
  xo[t + 256] = o1;
}

// ---------------- weight conversion ----------------
__global__ __launch_bounds__(256) void convert_gate_w(const float* __restrict__ Wi,
                                                      const float* __restrict__ Wf,
                                                      const float* __restrict__ Wo,
                                                      const float* __restrict__ Wc,
                                                      __hip_bfloat16* __restrict__ Wb) {
  int g = blockIdx.z;
  const float* W = (g == 0) ? Wi : (g == 1) ? Wf : (g == 2) ? Wo : Wc;
  size_t u = (size_t)blockIdx.x * 256 + threadIdx.x;  // float4 index, NP*512 per gate
  int j = (int)(u >> 9);
  int q = (int)(u & 511);
  ushort4 o;
  if (j < P_) {
    float4 v = ((const float4*)(W + (size_t)j * D_))[q];
    o.x = f2bf(v.x); o.y = f2bf(v.y); o.z = f2bf(v.z); o.w = f2bf(v.w);
  } else {
    o.x = 0; o.y = 0; o.z = 0; o.w = 0;
  }
  ushort4* dst = (ushort4*)(Wb + (size_t)g * NP * D_ + (size_t)j * D_ + (size_t)q * 4);
  *dst = o;
}

__global__ __launch_bounds__(256) void convert_wout(const float* __restrict__ Wout,
                                                    __hip_bfloat16* __restrict__ Woutb) {
  size_t u = (size_t)blockIdx.x * 256 + threadIdx.x;
  if (u >= (size_t)D_ * NP) return;
  int d = (int)(u / NP);
  int p = (int)(u - (size_t)d * NP);
  float v = (p < P_) ? Wout[(size_t)d * P_ + p] : 0.0f;
  Woutb[u] = __float2bfloat16(v);
}

// ---------------- 256x256 8-phase GEMM core (C = A * B^T), bf16 ----------------
// A: [M][LD], Bm: [N][LD], both K-contiguous. 512 threads = 8 waves (2Mx4N).
// LDS: [buf(2)][mat(2)][half(2)][128x64 bf16] = 128 KiB, XOR-swizzled reads,
// linear gload_lds dest + inverse-swizzled global source (rule #21).
// Even K-tiles -> buf0, odd -> buf1. One half-tile staged per phase; staging of a
// region is issued only in a phase strictly after all reads of its previous
// contents completed (barrier-lockstep). vmcnt placed BEFORE a barrier so all
// waves' own loads are drained before any wave reads (vmcnt is per-wave).
template <int LD, int NKT>
static __device__ __forceinline__ void gemm256_core(const ushort* __restrict__ A,
                                                    const ushort* __restrict__ Bm,
                                                    int tile_m, int tile_n,
                                                    ushort* lds, fx4 (&acc)[8][4]) {
  const int t = threadIdx.x;
  const int lane = t & 63;
  const int w = t >> 6;
  const int wr = w >> 2;            // 0..1  (M position of wave)
  const int wc = w & 3;             // 0..3  (N position of wave)
  const int frow = lane & 15;
  const int g = lane >> 4;
  const int xr = (frow & 7) << 4;   // read-side XOR swizzle (bits 4..6)

  // staging constants: thread t, round r covers lds bytes (r*512+t)*16
  const int rh0 = t >> 3;                               // row-in-half, round 0
  const int rh1 = 64 + rh0;                             // round 1
  const int cs = ((t & 7) ^ ((t >> 3) & 7)) << 3;       // pre-swizzled src col (elems)

  ushort* R[8];
#pragma unroll
  for (int i = 0; i < 8; ++i) R[i] = lds + i * 8192;    // buf*4 + mat*2 + half
  const ushort* RAu = R[0 + 0 + wr];
  const ushort* RBu = R[0 + 2 + (wc >> 1)];
  const ushort* RAv = R[4 + 0 + wr];
  const ushort* RBv = R[4 + 2 + (wc >> 1)];

  auto STAGE = [&](const ushort* src, int rowbase, int ktile, ushort* dst) {
    const ushort* g0 = src + (size_t)(rowbase + rh0) * LD + ktile * 64 + cs;
    const ushort* g1 = src + (size_t)(rowbase + rh1) * LD + ktile * 64 + cs;
    gload_lds16(g0, dst + t * 8);
    gload_lds16(g1, dst + 4096 + t * 8);
  };
  auto RD = [&](const ushort* reg, int rowInHalf, int kk) -> bh8 {
    return *(const bh8*)((const char*)reg + (rowInHalf << 7) + (((kk << 6) + (g << 4)) ^ xr));
  };

  // prologue: B(0,h0) B(0,h1) A(0,h0) A(0,h1) B(1,h0) B(1,h1); allow B(1) in flight
  STAGE(Bm, tile_n,       0, R[2]);
  STAGE(Bm, tile_n + 128, 0, R[3]);
  STAGE(A,  tile_m,       0, R[0]);
  STAGE(A,  tile_m + 128, 0, R[1]);
  STAGE(Bm, tile_n,       1, R[6]);
  STAGE(Bm, tile_n + 128, 1, R[7]);
  asm volatile("s_waitcnt vmcnt(4)" ::: "memory");
  __builtin_amdgcn_s_barrier();

  bh8 af[4][2], b0[2][2], b1[2][2];
  const int nIter = NKT / 2;

  for (int j = 0; j < nIter; ++j) {
    const int v = 2 * j + 1;
    const bool more = (j + 1 < nIter);

    // ---- ph1: tile u Q(0,0) [acc(0..3)(0..1)]; stage A(v,h0) ----
#pragma unroll
    for (int mi = 0; mi < 4; ++mi) {
      af[mi][0] = RD(RAu, mi * 16 + frow, 0);
      af[mi][1] = RD(RAu, mi * 16 + frow, 1);
    }
#pragma unroll
    for (int ni = 0; ni < 2; ++ni) {
      b0[ni][0] = RD(RBu, (wc & 1) * 64 + ni * 16 + frow, 0);
      b0[ni][1] = RD(RBu, (wc & 1) * 64 + ni * 16 + frow, 1);
    }
    STAGE(A, tile_m, v, R[4]);
    __builtin_amdgcn_sched_barrier(0);
    __builtin_amdgcn_s_barrier();
    __builtin_amdgcn_s_setprio(1);
#pragma unroll
    for (int mi = 0; mi < 4; ++mi)
#pragma unroll
      for (int ni = 0; ni < 2; ++ni) {
        acc[mi][ni] = __builtin_amdgcn_mfma_f32_16x16x32_bf16(af[mi][0], b0[ni][0], acc[mi][ni], 0, 0, 0);
        acc[mi][ni] = __builtin_amdgcn_mfma_f32_16x16x32_bf16(af[mi][1], b0[ni][1], acc[mi][ni], 0, 0, 0);
      }
    __builtin_amdgcn_s_setprio(0);
    __builtin_amdgcn_s_barrier();
    __builtin_amdgcn_sched_barrier(0);

    // ---- ph2: tile u Q(0,1) [acc(0..3)(2..3)]; stage A(v,h1) ----
#pragma unroll
    for (int ni = 0; ni < 2; ++ni) {
      b1[ni][0] = RD(RBu, (wc & 1) * 64 + (ni + 2) * 16 + frow, 0);
      b1[ni][1] = RD(RBu, (wc & 1) * 64 + (ni + 2) * 16 + frow, 1);
    }
    STAGE(A, tile_m + 128, v, R[5]);
    __builtin_amdgcn_sched_barrier(0);
    __builtin_amdgcn_s_barrier();
    __builtin_amdgcn_s_setprio(1);
#pragma unroll
    for (int mi = 0; mi < 4; ++mi)
#pragma unroll
      for (int ni = 0; ni < 2; ++ni) {
        acc[mi][ni + 2] = __builtin_amdgcn_mfma_f32_16x16x32_bf16(af[mi][0], b1[ni][0], acc[mi][ni + 2], 0, 0, 0);
        acc[mi][ni + 2] = __builtin_amdgcn_mfma_f32_16x16x32_bf16(af[mi][1], b1[ni][1], acc[mi][ni + 2], 0, 0, 0);
      }
    __builtin_amdgcn_s_setprio(0);
    __builtin_amdgcn_s_barrier();
    __builtin_amdgcn_sched_barrier(0);

    // ---- ph3: tile u Q(1,1) [acc(4..7)(2..3)]; stage B(u+2,h0) ----
#pragma unroll
    for (int mi = 0; mi < 4; ++mi) {
      af[mi][0] = RD(RAu, (mi + 4) * 16 + frow, 0);
      af[mi][1] = RD(RAu, (mi + 4) * 16 + frow, 1);
    }
    if (more) STAGE(Bm, tile_n, 2 * j + 2, R[2]);
    __builtin_amdgcn_sched_barrier(0);
    __builtin_amdgcn_s_barrier();
    __builtin_amdgcn_s_setprio(1);
#pragma unroll
    for (int mi = 0; mi < 4; ++mi)
#pragma unroll
      for (int ni = 0; ni < 2; ++ni) {
        acc[mi + 4][ni + 2] = __builtin_amdgcn_mfma_f32_16x16x32_bf16(af[mi][0], b1[ni][0], acc[mi + 4][ni + 2], 0, 0, 0);
        acc[mi + 4][ni + 2] = __builtin_amdgcn_mfma_f32_16x16x32_bf16(af[mi][1], b1[ni][1], acc[mi + 4][ni + 2], 0, 0, 0);
      }
    __builtin_amdgcn_s_setprio(0);
    __builtin_amdgcn_s_barrier();
    __builtin_amdgcn_sched_barrier(0);

    // ---- ph4: tile u Q(1,0) [acc(4..7)(0..1)]; stage B(u+2,h1); vmcnt gate ----
    if (more) STAGE(Bm, tile_n + 128, 2 * j + 2, R[3]);
    __builtin_amdgcn_sched_barrier(0);
    __builtin_amdgcn_s_barrier();
    __builtin_amdgcn_s_setprio(1);
#pragma unroll
    for (int mi = 0; mi < 4; ++mi)
#pragma unroll
      for (int ni = 0; ni < 2; ++ni) {
        acc[mi + 4][ni] = __builtin_amdgcn_mfma_f32_16x16x32_bf16(af[mi][0], b0[ni][0], acc[mi + 4][ni], 0, 0, 0);
        acc[mi + 4][ni] = __builtin_amdgcn_mfma_f32_16x16x32_bf16(af[mi][1], b0[ni][1], acc[mi + 4][ni], 0, 0, 0);
      }
    __builtin_amdgcn_s_setprio(0);
    if (more) { asm volatile("s_waitcnt vmcnt(4)" ::: "memory"); }
    else      { asm volatile("s_waitcnt vmcnt(0)" ::: "memory"); }
    __builtin_amdgcn_s_barrier();
    __builtin_amdgcn_sched_barrier(0);

    // ---- ph5: tile v Q(0,0); stage A(u+2,h0) ----
#pragma unroll
    for (int mi = 0; mi < 4; ++mi) {
      af[mi][0] = RD(RAv, mi * 16 + frow, 0);
      af[mi][1] = RD(RAv, mi * 16 + frow, 1);
    }
#pragma unroll
    for (int ni = 0; ni < 2; ++ni) {
      b0[ni][0] = RD(RBv, (wc & 1) * 64 + ni * 16 + frow, 0);
      b0[ni][1] = RD(RBv, (wc & 1) * 64 + ni * 16 + frow, 1);
    }
    if (more) STAGE(A, tile_m, 2 * j + 2, R[0]);
    __builtin_amdgcn_sched_barrier(0);
    __builtin_amdgcn_s_barrier();
    __builtin_amdgcn_s_setprio(1);
#pragma unroll
    for (int mi = 0; mi < 4; ++mi)
#pragma unroll
      for (int ni = 0; ni < 2; ++ni) {
        acc[mi][ni] = __builtin_amdgcn_mfma_f32_16x16x32_bf16(af[mi][0], b0[ni][0], acc[mi][ni], 0, 0, 0);
        acc[mi][ni] = __builtin_amdgcn_mfma_f32_16x16x32_bf16(af[mi][1], b0[ni][1], acc[mi][ni], 0, 0, 0);
      }
    __builtin_amdgcn_s_setprio(0);
    __builtin_amdgcn_s_barrier();
    __builtin_amdgcn_sched_barrier(0);

    // ---- ph6: tile v Q(0,1); stage A(u+2,h1) ----
#pragma unroll
    for (int ni = 0; ni < 2; ++ni) {
      b1[ni][0] = RD(RBv, (wc & 1) * 64 + (ni + 2) * 16 + frow, 0);
      b1[ni][1] = RD(RBv, (wc & 1) * 64 + (ni + 2) * 16 + frow, 1);
    }
    if (more) STAGE(A, tile_m + 128, 2 * j + 2, R[1]);
    __builtin_amdgcn_sched_barrier(0);
    __builtin_amdgcn_s_barrier();
    __builtin_amdgcn_s_setprio(1);
#pragma unroll
    for (int mi = 0; mi < 4; ++mi)
#pragma unroll
      for (int ni = 0; ni < 2; ++ni) {
        acc[mi][ni + 2] = __builtin_amdgcn_mfma_f32_16x16x32_bf16(af[mi][0], b1[ni][0], acc[mi][ni + 2], 0, 0, 0);
        acc[mi][ni + 2] = __builtin_amdgcn_mfma_f32_16x16x32_bf16(af[mi][1], b1[ni][1], acc[mi][ni + 2], 0, 0, 0);
      }
    __builtin_amdgcn_s_setprio(0);
    __builtin_amdgcn_s_barrier();
    __builtin_amdgcn_sched_barrier(0);

    // ---- ph7: tile v Q(1,1); stage B(v+2,h0) ----
#pragma unroll
    for (int mi = 0; mi < 4; ++mi) {
      af[mi][0] = RD(RAv, (mi + 4) * 16 + frow, 0);
      af[mi][1] = RD(RAv, (mi + 4) * 16 + frow, 1);
    }
    if (more) STAGE(Bm, tile_n, 2 * j + 3, R[6]);
    __builtin_amdgcn_sched_barrier(0);
    __builtin_amdgcn_s_barrier();
    __builtin_amdgcn_s_setprio(1);
#pragma unroll
    for (int mi = 0; mi < 4; ++mi)
#pragma unroll
      for (int ni = 0; ni < 2; ++ni) {
        acc[mi + 4][ni + 2] = __builtin_amdgcn_mfma_f32_16x16x32_bf16(af[mi][0], b1[ni][0], acc[mi + 4][ni + 2], 0, 0, 0);
        acc[mi + 4][ni + 2] = __builtin_amdgcn_mfma_f32_16x16x32_bf16(af[mi][1], b1[ni][1], acc[mi + 4][ni + 2], 0, 0, 0);
      }
    __builtin_amdgcn_s_setprio(0);
    __builtin_amdgcn_s_barrier();
    __builtin_amdgcn_sched_barrier(0);

    // ---- ph8: tile v Q(1,0); stage B(v+2,h1); vmcnt gate for next iter ----
    if (more) STAGE(Bm, tile_n + 128, 2 * j + 3, R[7]);
    __builtin_amdgcn_sched_barrier(0);
    __builtin_amdgcn_s_barrier();
    __builtin_amdgcn_s_setprio(1);
#pragma unroll
    for (int mi = 0; mi < 4; ++mi)
#pragma unroll
      for (int ni = 0; ni < 2; ++ni) {
        acc[mi + 4][ni] = __builtin_amdgcn_mfma_f32_16x16x32_bf16(af[mi][0], b0[ni][0], acc[mi + 4][ni], 0, 0, 0);
        acc[mi + 4][ni] = __builtin_amdgcn_mfma_f32_16x16x32_bf16(af[mi][1], b0[ni][1], acc[mi + 4][ni], 0, 0, 0);
      }
    __builtin_amdgcn_s_setprio(0);
    if (more) {
      asm volatile("s_waitcnt vmcnt(4)" ::: "memory");
      __builtin_amdgcn_s_barrier();
    }
    __builtin_amdgcn_sched_barrier(0);
  }
}

// Gate GEMM: gates[g][m][n] = act(sum_d xn[m][d] * Wb[g][n][d])
__global__ __launch_bounds__(512, 2) void gemm_gates(const __hip_bfloat16* __restrict__ A,
                                                     const __hip_bfloat16* __restrict__ Wb,
                                                     __hip_bfloat16* __restrict__ G) {
  __shared__ ushort lds[8 * 8192];  // 128 KiB
  int gate = blockIdx.z;
  // bijective XCD swizzle: nwg=352, q=44
  int lin = blockIdx.x + 11 * blockIdx.y;
  int wg = (lin & 7) * 44 + (lin >> 3);
  int bx = wg % 11, by = wg / 11;
  int tile_n = bx * 256;
  int tile_m = by * 256;

  const ushort* Am = (const ushort*)A;
  const ushort* Bm = (const ushort*)Wb + (size_t)gate * NP * D_;
  __hip_bfloat16* Gg = G + (size_t)gate * M_ * NP;

  fx4 acc[8][4];
#pragma unroll
  for (int i = 0; i < 8; ++i)
#pragma unroll
    for (int j = 0; j < 4; ++j) acc[i][j] = (fx4){0.f, 0.f, 0.f, 0.f};

  gemm256_core<D_, D_ / 64>(Am, Bm, tile_m, tile_n, lds, acc);

  int lane = threadIdx.x & 63;
  int w = threadIdx.x >> 6;
  int wr = w >> 2, wc = w & 3;
  int g = lane >> 4;
#pragma unroll
  for (int mf = 0; mf < 8; ++mf) {
    int mbase = tile_m + wr * 128 + mf * 16 + (g << 2);
#pragma unroll
    for (int nf = 0; nf < 4; ++nf) {
      int n = tile_n + wc * 64 + nf * 16 + (lane & 15);
      bool valid = (n < P_);
#pragma unroll
      for (int r = 0; r < 4; ++r) {
        float z = acc[mf][nf][r];
        float val = (gate == 3) ? fast_tanh(z) : gate_act(z);
        if (!valid) val = 0.0f;
        Gg[(size_t)(mbase + r) * NP + n] = __float2bfloat16(val);
      }
    }
  }
}

// Output GEMM: out[m][n] = x[m][n] + sum_p outbuf[m][p] * Woutb[n][p]
__global__ __launch_bounds__(512, 2) void gemm_out(const __hip_bfloat16* __restrict__ A,
                                                   const __hip_bfloat16* __restrict__ Bw,
                                                   const float* __restrict__ X,
                                                   float* __restrict__ Out) {
  __shared__ ushort lds[8 * 8192];
  // bijective XCD swizzle: nwg=256, q=32
  int lin = blockIdx.x + 8 * blockIdx.y;
  int wg = (lin & 7) * 32 + (lin >> 3);
  int bx = wg & 7, by = wg >> 3;
  int tile_n = bx * 256;
  int tile_m = by * 256;

  fx4 acc[8][4];
#pragma unroll
  for (int i = 0; i < 8; ++i)
#pragma unroll
    for (int j = 0; j < 4; ++j) acc[i][j] = (fx4){0.f, 0.f, 0.f, 0.f};

  gemm256_core<NP, NP / 64>((const ushort*)A, (const ushort*)Bw, tile_m, tile_n, lds, acc);

  int lane = threadIdx.x & 63;
  int w = threadIdx.x >> 6;
  int wr = w >> 2, wc = w & 3;
  int g = lane >> 4;
#pragma unroll
  for (int mf = 0; mf < 8; ++mf) {
    int mbase = tile_m + wr * 128 + mf * 16 + (g << 2);
#pragma unroll
    for (int nf = 0; nf < 4; ++nf) {
      int n = tile_n + wc * 64 + nf * 16 + (lane & 15);
#pragma unroll
      for (int r = 0; r < 4; ++r) {
        size_t o = (size_t)(mbase + r) * D_ + n;
        Out[o] = X[o] + acc[mf][nf][r];
      }
    }
  }
}

// ---------------- chunked parallel LSTM scan (h = f*h + u is linear in h) ----------------
// pass1: per chunk c, per (b,p): a = prod f, bacc = h_end(h_start=0)
__global__ __launch_bounds__(256) void scan_pass1(const __hip_bfloat16* __restrict__ G,
                                                  float* __restrict__ Aa, float* __restrict__ Bb) {
  int idx = blockIdx.x * 256 + threadIdx.x;  // (b,p) flat, 0..B_*NP-1
  int c = blockIdx.y;
  int b = idx / NP, p = idx - b * NP;
  size_t base = ((size_t)(b * S_ + c * SCHUNK)) * NP + p;
  const unsigned short* gi = (const unsigned short*)G + base;
  const size_t gs = (size_t)M_ * NP;
  const unsigned short* gf = gi + gs;
  const unsigned short* gc = gi + 3 * gs;
  float a = 1.f, acc = 0.f;
#pragma unroll 8
  for (int s = 0; s < SCHUNK; ++s) {
    size_t off = (size_t)s * NP;
    float fv = bf2f(gf[off]);
    float u = bf2f(gi[off]) * bf2f(gc[off]);
    acc = fv * acc + u;
    a *= fv;
  }
  int o = c * (B_ * NP) + idx;
  Aa[o] = a;
  Bb[o] = acc;
}

// mid: serial scan over the 16 chunks; emit chunk-start states + final h
__global__ __launch_bounds__(256) void scan_mid(const float* __restrict__ Aa,
                                                const float* __restrict__ Bb,
                                                const float* __restrict__ h0,
                                                float* __restrict__ Hs,
                                                float* __restrict__ hfin) {
  int idx = blockIdx.x * 256 + threadIdx.x;
  int b = idx / NP, p = idx - b * NP;
  float h = (p < P_) ? h0[b * P_ + p] : 0.f;
#pragma unroll
  for (int c = 0; c < NCHUNK; ++c) {
    int o = c * (B_ * NP) + idx;
    Hs[o] = h;
    h = Aa[o] * h + Bb[o];
  }
  if (p < P_) hfin[b * P_ + p] = h;
}

// pass2: replay chunks in parallel from known start state; write o*tanh(h)
__global__ __launch_bounds__(256) void scan_pass2(const __hip_bfloat16* __restrict__ G,
                                                  const float* __restrict__ Hs,
                                                  __hip_bfloat16* __restrict__ outb) {
  int idx = blockIdx.x * 256 + threadIdx.x;
  int c = blockIdx.y;
  int b = idx / NP, p = idx - b * NP;
  size_t base = ((size_t)(b * S_ + c * SCHUNK)) * NP + p;
  const unsigned short* gi = (const unsigned short*)G + base;
  const size_t gs = (size_t)M_ * NP;
  const unsigned short* gf = gi + gs;
  const unsigned short* go = gi + 2 * gs;
  const unsigned short* gc = gi + 3 * gs;
  unsigned short* ob = (unsigned short*)outb + base;
  float h = Hs[c * (B_ * NP) + idx];
#pragma unroll 4
  for (int s = 0; s < SCHUNK; ++s) {
    size_t off = (size_t)s * NP;
    float u = bf2f(gi[off]) * bf2f(gc[off]);
    h = bf2f(gf[off]) * h + u;
    ob[off] = f2bf(bf2f(go[off]) * fast_tanh(h));
  }
}

// ---------------- launch ----------------
extern "C" void kernel_launch(void* const* d_in, const int* in_sizes, int n_in,
                              void* d_out, int out_size, void* d_ws, size_t ws_size,
                              hipStream_t stream) {
  const float* x    = (const float*)d_in[0];
  const float* h0   = (const float*)d_in[1];
  const float* Wi   = (const float*)d_in[2];
  const float* Wf   = (const float*)d_in[3];
  const float* Wo   = (const float*)d_in[4];
  const float* Wc   = (const float*)d_in[5];
  const float* Wout = (const float*)d_in[6];
  const float* lnw  = (const float*)d_in[7];
  float* out  = (float*)d_out;
  float* hfin = out + (size_t)M_ * D_;

  // workspace layout (bf16 elems):
  //   phase 1: xn [0, 16.78M), Wb [16.78M, 39.85M), gates [39.85M, 132.1M)
  //   phase 2: outbuf [0, 23.07M), Woutb [23.07M, 28.84M), scan f32 scratch [28.84M, ~29.9M)
  const size_t wb_off    = (size_t)M_ * D_;                    // 16,777,216
  const size_t gates_off = wb_off + (size_t)4 * NP * D_;       // 39,845,888
  const size_t need = (gates_off + (size_t)4 * M_ * NP) * 2;   // bytes
  if (ws_size < need) {
    fprintf(stderr, "kernel_launch: ws too small (%zu < %zu)\n", ws_size, need);
    return;
  }
  __hip_bfloat16* ws     = (__hip_bfloat16*)d_ws;
  __hip_bfloat16* xn     = ws;
  __hip_bfloat16* Wb     = ws + wb_off;
  __hip_bfloat16* Gg     = ws + gates_off;
  __hip_bfloat16* outbuf = ws;                                  // aliases xn/Wb (dead)
  __hip_bfloat16* Woutb  = ws + (size_t)M_ * NP;
  float* scr = (float*)(ws + (size_t)M_ * NP + (size_t)D_ * NP); // 28,835,840 elems in
  float* Aa = scr;
  float* Bb = Aa + NCHUNK * B_ * NP;
  float* Hs = Bb + NCHUNK * B_ * NP;

  convert_gate_w<<<dim3(NP * 512 / 256, 1, 4), 256, 0, stream>>>(Wi, Wf, Wo, Wc, Wb);
  rmsnorm_kernel<<<M_, 256, 0, stream>>>(x, lnw, xn);
  gemm_gates<<<dim3(NP / 256, M_ / 256, 4), 512, 0, stream>>>(xn, Wb, Gg);
  convert_wout<<<(int)(((size_t)D_ * NP + 255) / 256), 256, 0, stream>>>(Wout, Woutb);
  scan_pass1<<<dim3(B_ * NP / 256, NCHUNK), 256, 0, stream>>>(Gg, Aa, Bb);
  scan_mid<<<B_ * NP / 256, 256, 0, stream>>>(Aa, Bb, h0, Hs, hfin);
  scan_pass2<<<dim3(B_ * NP / 256, NCHUNK), 256, 0, stream>>>(Gg, Hs, outbuf);
  gemm_out<<<dim3(D_ / 256, M_ / 256), 512, 0, stream>>>(outbuf, Woutb, x, out);
}

// Round 3
// 708.576 us; speedup vs baseline: 2.8343x; 2.8343x over previous
//
#include <hip/hip_runtime.h>
#include <hip/hip_bf16.h>
#include <stdint.h>
#include <stdio.h>

// Problem sizes (fixed by setup_inputs)
#define B_ 4
#define S_ 2048
#define D_ 2048
#define P_ 2729
#define NP 2816            // P padded to multiple of 128
#define M_ (B_ * S_)       // 8192

#define SCHUNK 128
#define NCHUNK (S_ / SCHUNK)   // 16

// GEMM tile: 128x128, BK=64, 4 waves (2x2), XOR-swizzled LDS
#define BM 128
#define BN 128
#define BK 64

typedef __attribute__((ext_vector_type(8))) short bh8;   // 8 x bf16 (4 VGPRs)
typedef __attribute__((ext_vector_type(4))) float fx4;   // MFMA accumulator

static __device__ __forceinline__ float bf2f(unsigned short u) {
  union { unsigned int i; float f; } c;
  c.i = ((unsigned int)u) << 16;
  return c.f;
}
static __device__ __forceinline__ unsigned short f2bf(float f) {
  union { __hip_bfloat16 h; unsigned short u; } c;
  c.h = __float2bfloat16(f);
  return c.u;
}
static __device__ __forceinline__ float fast_tanh(float x) {
  return 1.0f - 2.0f / (__expf(2.0f * x) + 1.0f);
}
static __device__ __forceinline__ float gate_act(float z) {
  float sc = 15.0f * fast_tanh(z * (1.0f / 15.0f));
  return 1.0f / (1.0f + __expf(-sc));
}

static __device__ __forceinline__ void gload_lds16(const ushort* g, ushort* l) {
  __builtin_amdgcn_global_load_lds(
      (const __attribute__((address_space(1))) unsigned int*)g,
      (__attribute__((address_space(3))) unsigned int*)l, 16, 0, 0);
}

// ---------------- RMSNorm + bf16 cast ----------------
__global__ __launch_bounds__(256) void rmsnorm_kernel(const float* __restrict__ x,
                                                      const float* __restrict__ w,
                                                      __hip_bfloat16* __restrict__ xn) {
  int row = blockIdx.x;
  const float4* xr = (const float4*)(x + (size_t)row * D_);
  int t = threadIdx.x;
  float4 v0 = xr[t];
  float4 v1 = xr[t + 256];
  float ss = v0.x * v0.x + v0.y * v0.y + v0.z * v0.z + v0.w * v0.w +
             v1.x * v1.x + v1.y * v1.y + v1.z * v1.z + v1.w * v1.w;
#pragma unroll
  for (int off = 32; off > 0; off >>= 1) ss += __shfl_down(ss, off);
  __shared__ float red[4];
  if ((t & 63) == 0) red[t >> 6] = ss;
  __syncthreads();
  float scale = rsqrtf((red[0] + red[1] + red[2] + red[3]) * (1.0f / (float)D_) + 1e-6f);
  const float4* wp = (const float4*)w;
  float4 w0 = wp[t], w1 = wp[t + 256];
  ushort4 o0, o1;
  o0.x = f2bf(v0.x * scale * w0.x);
  o0.y = f2bf(v0.y * scale * w0.y);
  o0.z = f2bf(v0.z * scale * w0.z);
  o0.w = f2bf(v0.w * scale * w0.w);
  o1.x = f2bf(v1.x * scale * w1.x);
  o1.y = f2bf(v1.y * scale * w1.y);
  o1.z = f2bf(v1.z * scale * w1.z);
  o1.w = f2bf(v1.w * scale * w1.w);
  ushort4* xo = (ushort4*)(xn + (size_t)row * D_);
  xo[t] = o0;
  xo[t + 256] = o1;
}

// ---------------- weight conversion ----------------
__global__ __launch_bounds__(256) void convert_gate_w(const float* __restrict__ Wi,
                                                      const float* __restrict__ Wf,
                                                      const float* __restrict__ Wo,
                                                      const float* __restrict__ Wc,
                                                      __hip_bfloat16* __restrict__ Wb) {
  int g = blockIdx.z;
  const float* W = (g == 0) ? Wi : (g == 1) ? Wf : (g == 2) ? Wo : Wc;
  size_t u = (size_t)blockIdx.x * 256 + threadIdx.x;  // float4 index, NP*512 per gate
  int j = (int)(u >> 9);
  int q = (int)(u & 511);
  ushort4 o;
  if (j < P_) {
    float4 v = ((const float4*)(W + (size_t)j * D_))[q];
    o.x = f2bf(v.x); o.y = f2bf(v.y); o.z = f2bf(v.z); o.w = f2bf(v.w);
  } else {
    o.x = 0; o.y = 0; o.z = 0; o.w = 0;
  }
  ushort4* dst = (ushort4*)(Wb + (size_t)g * NP * D_ + (size_t)j * D_ + (size_t)q * 4);
  *dst = o;
}

__global__ __launch_bounds__(256) void convert_wout(const float* __restrict__ Wout,
                                                    __hip_bfloat16* __restrict__ Woutb) {
  size_t u = (size_t)blockIdx.x * 256 + threadIdx.x;
  if (u >= (size_t)D_ * NP) return;
  int d = (int)(u / NP);
  int p = (int)(u - (size_t)d * NP);
  float v = (p < P_) ? Wout[(size_t)d * P_ + p] : 0.0f;
  Woutb[u] = __float2bfloat16(v);
}

// ---------------- GEMM core (C = A * B^T), bf16, 128x128 tile, BK=64 ----------------
// A: [M][LD] row-major, B: [N][LD] row-major (K contiguous both).
// LDS tiles [128 rows][64 cols] bf16 = 16 KB each; row = 128 B -> full 8-slot
// XOR swizzle (byte ^= (row&7)<<4) kills the BK=32 structure's 8-way read
// conflict. gload_lds dest stays LINEAR (HW constraint m104); the read-side
// permutation is compensated by pre-swizzling the GLOBAL source column
// (rule #21: same involution on source and read).
template <int LD, int KTOT>
static __device__ __forceinline__ void gemm_core(const ushort* __restrict__ A,
                                                 const ushort* __restrict__ Bm,
                                                 int tile_m, int tile_n,
                                                 ushort* lA, ushort* lB,
                                                 fx4 (&acc)[4][4]) {
  const int t = threadIdx.x;
  const int lane = t & 63;
  const int w = t >> 6;
  const int wr = w >> 1, wc = w & 1;
  const int frow = lane & 15;
  const int g = lane >> 4;
  const int xr = (frow & 7) << 4;

  // staging: thread t, round q: LDS elements (q*256+t)*8 (linear),
  // row r = (q*256+t)>>3, global col = ((t&7) ^ (r&7)) * 8 + k0
  const ushort* gA[4];
  const ushort* gB[4];
  int ldsoff[4];
#pragma unroll
  for (int q = 0; q < 4; ++q) {
    int u = q * 256 + t;
    int r = u >> 3;
    int gc = ((t & 7) ^ (r & 7)) << 3;
    gA[q] = A + (size_t)(tile_m + r) * LD + gc;
    gB[q] = Bm + (size_t)(tile_n + r) * LD + gc;
    ldsoff[q] = u * 8;
  }

  const char* baseA = (const char*)lA + ((wr * 64 + frow) << 7);
  const char* baseB = (const char*)lB + ((wc * 64 + frow) << 7);
  const int c0 = (g * 16) ^ xr;        // kk=0 16B slot (swizzled)
  const int c1 = (64 + g * 16) ^ xr;   // kk=1 16B slot (swizzled)

  for (int k0 = 0; k0 < KTOT; k0 += BK) {
#pragma unroll
    for (int q = 0; q < 4; ++q) gload_lds16(gA[q] + k0, lA + ldsoff[q]);
#pragma unroll
    for (int q = 0; q < 4; ++q) gload_lds16(gB[q] + k0, lB + ldsoff[q]);
    __syncthreads();  // vmcnt(0)+lgkmcnt(0) drain -> LDS valid for all waves
    bh8 af[4][2], bf[4][2];
#pragma unroll
    for (int mf = 0; mf < 4; ++mf) {
      af[mf][0] = *(const bh8*)(baseA + (mf << 11) + c0);
      af[mf][1] = *(const bh8*)(baseA + (mf << 11) + c1);
    }
#pragma unroll
    for (int nf = 0; nf < 4; ++nf) {
      bf[nf][0] = *(const bh8*)(baseB + (nf << 11) + c0);
      bf[nf][1] = *(const bh8*)(baseB + (nf << 11) + c1);
    }
#pragma unroll
    for (int mf = 0; mf < 4; ++mf)
#pragma unroll
      for (int nf = 0; nf < 4; ++nf) {
        acc[mf][nf] = __builtin_amdgcn_mfma_f32_16x16x32_bf16(af[mf][0], bf[nf][0], acc[mf][nf], 0, 0, 0);
        acc[mf][nf] = __builtin_amdgcn_mfma_f32_16x16x32_bf16(af[mf][1], bf[nf][1], acc[mf][nf], 0, 0, 0);
      }
    __syncthreads();  // all waves done reading before next stage overwrites
  }
}

// Gate GEMM: gates[g][m][n] = act(sum_d xn[m][d] * Wb[g][n][d])
__global__ __launch_bounds__(256) void gemm_gates(const __hip_bfloat16* __restrict__ A,
                                                  const __hip_bfloat16* __restrict__ Wb,
                                                  __hip_bfloat16* __restrict__ G) {
  int gate = blockIdx.z;
  // XCD chunked swizzle: nwg=1408 per gate slice, chunk=176 -> each XCD owns
  // 8 consecutive tile-rows (A-panel 8*128 rows x 2048 x 2B = 4 MB = L2)
  int lin = blockIdx.x + 22 * blockIdx.y;
  int wg = (lin & 7) * 176 + (lin >> 3);
  int bx = wg % 22, by = wg / 22;
  int tile_n = bx * BN;
  int tile_m = by * BM;

  const ushort* Bm = (const ushort*)Wb + (size_t)gate * NP * D_;
  __hip_bfloat16* Gg = G + (size_t)gate * M_ * NP;

  __shared__ ushort lA[BM * BK];
  __shared__ ushort lB[BN * BK];

  fx4 acc[4][4];
#pragma unroll
  for (int i = 0; i < 4; ++i)
#pragma unroll
    for (int j = 0; j < 4; ++j) acc[i][j] = (fx4){0.f, 0.f, 0.f, 0.f};

  gemm_core<D_, D_>((const ushort*)A, Bm, tile_m, tile_n, lA, lB, acc);

  int lane = threadIdx.x & 63;
  int w = threadIdx.x >> 6;
  int wr = w >> 1, wc = w & 1;
#pragma unroll
  for (int mf = 0; mf < 4; ++mf) {
    int mbase = tile_m + wr * 64 + mf * 16 + ((lane >> 4) << 2);
#pragma unroll
    for (int nf = 0; nf < 4; ++nf) {
      int n = tile_n + wc * 64 + nf * 16 + (lane & 15);
      bool valid = (n < P_);
#pragma unroll
      for (int r = 0; r < 4; ++r) {
        float z = acc[mf][nf][r];
        float val = (gate == 3) ? fast_tanh(z) : gate_act(z);
        if (!valid) val = 0.0f;
        Gg[(size_t)(mbase + r) * NP + n] = __float2bfloat16(val);
      }
    }
  }
}

// Output GEMM: out[m][n] = x[m][n] + sum_p outbuf[m][p] * Woutb[n][p]
__global__ __launch_bounds__(256) void gemm_out(const __hip_bfloat16* __restrict__ A,
                                               const __hip_bfloat16* __restrict__ Bw,
                                               const float* __restrict__ X,
                                               float* __restrict__ Out) {
  // XCD chunked swizzle: nwg=1024, chunk=128
  int lin = blockIdx.x + 16 * blockIdx.y;
  int wg = (lin & 7) * 128 + (lin >> 3);
  int bx = wg & 15, by = wg >> 4;
  int tile_n = bx * BN;
  int tile_m = by * BM;

  __shared__ ushort lA[BM * BK];
  __shared__ ushort lB[BN * BK];

  fx4 acc[4][4];
#pragma unroll
  for (int i = 0; i < 4; ++i)
#pragma unroll
    for (int j = 0; j < 4; ++j) acc[i][j] = (fx4){0.f, 0.f, 0.f, 0.f};

  gemm_core<NP, NP>((const ushort*)A, (const ushort*)Bw, tile_m, tile_n, lA, lB, acc);

  int lane = threadIdx.x & 63;
  int w = threadIdx.x >> 6;
  int wr = w >> 1, wc = w & 1;
#pragma unroll
  for (int mf = 0; mf < 4; ++mf) {
    int mbase = tile_m + wr * 64 + mf * 16 + ((lane >> 4) << 2);
#pragma unroll
    for (int nf = 0; nf < 4; ++nf) {
      int n = tile_n + wc * 64 + nf * 16 + (lane & 15);
#pragma unroll
      for (int r = 0; r < 4; ++r) {
        size_t o = (size_t)(mbase + r) * D_ + n;
        Out[o] = X[o] + acc[mf][nf][r];
      }
    }
  }
}

// ---------------- chunked parallel LSTM scan (h = f*h + u is linear in h) ----------------
// pass1: per chunk c, per (b,p): a = prod f, bacc = h_end(h_start=0)
__global__ __launch_bounds__(256) void scan_pass1(const __hip_bfloat16* __restrict__ G,
                                                  float* __restrict__ Aa, float* __restrict__ Bb) {
  int idx = blockIdx.x * 256 + threadIdx.x;  // (b,p) flat
  int c = blockIdx.y;
  int b = idx / NP, p = idx - b * NP;
  size_t base = ((size_t)(b * S_ + c * SCHUNK)) * NP + p;
  const unsigned short* gi = (const unsigned short*)G + base;
  const size_t gs = (size_t)M_ * NP;
  const unsigned short* gf = gi + gs;
  const unsigned short* gc = gi + 3 * gs;
  float a = 1.f, acc = 0.f;
#pragma unroll 8
  for (int s = 0; s < SCHUNK; ++s) {
    size_t off = (size_t)s * NP;
    float fv = bf2f(gf[off]);
    float u = bf2f(gi[off]) * bf2f(gc[off]);
    acc = fv * acc + u;
    a *= fv;
  }
  int o = c * (B_ * NP) + idx;
  Aa[o] = a;
  Bb[o] = acc;
}

// mid: serial scan over the 16 chunks; emit chunk-start states + final h
__global__ __launch_bounds__(256) void scan_mid(const float* __restrict__ Aa,
                                                const float* __restrict__ Bb,
                                                const float* __restrict__ h0,
                                                float* __restrict__ Hs,
                                                float* __restrict__ hfin) {
  int idx = blockIdx.x * 256 + threadIdx.x;
  int b = idx / NP, p = idx - b * NP;
  float h = (p < P_) ? h0[b * P_ + p] : 0.f;
#pragma unroll
  for (int c = 0; c < NCHUNK; ++c) {
    int o = c * (B_ * NP) + idx;
    Hs[o] = h;
    h = Aa[o] * h + Bb[o];
  }
  if (p < P_) hfin[b * P_ + p] = h;
}

// pass2: replay chunks in parallel from known start state; write o*tanh(h)
__global__ __launch_bounds__(256) void scan_pass2(const __hip_bfloat16* __restrict__ G,
                                                  const float* __restrict__ Hs,
                                                  __hip_bfloat16* __restrict__ outb) {
  int idx = blockIdx.x * 256 + threadIdx.x;
  int c = blockIdx.y;
  int b = idx / NP, p = idx - b * NP;
  size_t base = ((size_t)(b * S_ + c * SCHUNK)) * NP + p;
  const unsigned short* gi = (const unsigned short*)G + base;
  const size_t gs = (size_t)M_ * NP;
  const unsigned short* gf = gi + gs;
  const unsigned short* go = gi + 2 * gs;
  const unsigned short* gc = gi + 3 * gs;
  unsigned short* ob = (unsigned short*)outb + base;
  float h = Hs[c * (B_ * NP) + idx];
#pragma unroll 4
  for (int s = 0; s < SCHUNK; ++s) {
    size_t off = (size_t)s * NP;
    float u = bf2f(gi[off]) * bf2f(gc[off]);
    h = bf2f(gf[off]) * h + u;
    ob[off] = f2bf(bf2f(go[off]) * fast_tanh(h));
  }
}

// ---------------- launch ----------------
extern "C" void kernel_launch(void* const* d_in, const int* in_sizes, int n_in,
                              void* d_out, int out_size, void* d_ws, size_t ws_size,
                              hipStream_t stream) {
  const float* x    = (const float*)d_in[0];
  const float* h0   = (const float*)d_in[1];
  const float* Wi   = (const float*)d_in[2];
  const float* Wf   = (const float*)d_in[3];
  const float* Wo   = (const float*)d_in[4];
  const float* Wc   = (const float*)d_in[5];
  const float* Wout = (const float*)d_in[6];
  const float* lnw  = (const float*)d_in[7];
  float* out  = (float*)d_out;
  float* hfin = out + (size_t)M_ * D_;

  // workspace layout (bf16 elems):
  //   phase 1: xn [0, 16.78M), Wb [16.78M, 39.85M), gates [39.85M, 132.1M)
  //   phase 2: outbuf [0, 23.07M), Woutb [23.07M, 28.84M), scan f32 scratch after
  const size_t wb_off    = (size_t)M_ * D_;                    // 16,777,216
  const size_t gates_off = wb_off + (size_t)4 * NP * D_;       // 39,845,888
  const size_t need = (gates_off + (size_t)4 * M_ * NP) * 2;   // bytes
  if (ws_size < need) {
    fprintf(stderr, "kernel_launch: ws too small (%zu < %zu)\n", ws_size, need);
    return;
  }
  __hip_bfloat16* ws     = (__hip_bfloat16*)d_ws;
  __hip_bfloat16* xn     = ws;
  __hip_bfloat16* Wb     = ws + wb_off;
  __hip_bfloat16* Gg     = ws + gates_off;
  __hip_bfloat16* outbuf = ws;                                  // aliases xn/Wb (dead)
  __hip_bfloat16* Woutb  = ws + (size_t)M_ * NP;
  float* scr = (float*)(ws + (size_t)M_ * NP + (size_t)D_ * NP); // after Woutb, < gates
  float* Aa = scr;
  float* Bb = Aa + NCHUNK * B_ * NP;
  float* Hs = Bb + NCHUNK * B_ * NP;

  convert_gate_w<<<dim3(NP * 512 / 256, 1, 4), 256, 0, stream>>>(Wi, Wf, Wo, Wc, Wb);
  rmsnorm_kernel<<<M_, 256, 0, stream>>>(x, lnw, xn);
  gemm_gates<<<dim3(NP / BN, M_ / BM, 4), 256, 0, stream>>>(xn, Wb, Gg);
  convert_wout<<<(int)(((size_t)D_ * NP + 255) / 256), 256, 0, stream>>>(Wout, Woutb);
  scan_pass1<<<dim3(B_ * NP / 256, NCHUNK), 256, 0, stream>>>(Gg, Aa, Bb);
  scan_mid<<<B_ * NP / 256, 256, 0, stream>>>(Aa, Bb, h0, Hs, hfin);
  scan_pass2<<<dim3(B_ * NP / 256, NCHUNK), 256, 0, stream>>>(Gg, Hs, outbuf);
  gemm_out<<<dim3(D_ / BN, M_ / BM), 256, 0, stream>>>(outbuf, Woutb, x, out);
}